// Round 1
// baseline (158.257 us; speedup 1.0000x reference)
//
#include <hip/hip_runtime.h>
#include <math.h>

// QK projection layer: scan -> GEMM reformulation (all fp32).
//   S = Q K^T (causal-masked, materialized in ws)
//   r_t = 2*sum_{s<t} G[t][s]^2 + G[t][t]^2 (+ 2 k^T Pprev k if Pprev != 0), G = K K^T
//   fro2[t] = ||Pprev||^2 + prefix(r)  -> invfro
//   Y = tril(S) @ K (+ Q Pprev^T)  -> q_out = tanh(gain*Y*invfro)*oscale
//   P_final = Pprev + K^T K

#define LDSPAD 68  // float stride, 16B-aligned, bank-spread

__global__ void k_base(const float* __restrict__ Pprev, float* __restrict__ base, int D) {
    int b = blockIdx.x;
    const float* P = Pprev + (size_t)b * D * D;
    int n = D * D;
    float s = 0.f;
    for (int i = threadIdx.x * 4; i < n; i += blockDim.x * 4) {
        float4 v = *(const float4*)(P + i);
        s += v.x * v.x + v.y * v.y + v.z * v.z + v.w * v.w;
    }
    for (int off = 32; off; off >>= 1) s += __shfl_down(s, off);
    __shared__ float wsum[8];
    int wid = threadIdx.x >> 6, lane = threadIdx.x & 63;
    if (lane == 0) wsum[wid] = s;
    __syncthreads();
    if (threadIdx.x == 0) {
        float t = 0.f;
        int nw = blockDim.x >> 6;
        for (int i = 0; i < nw; i++) t += wsum[i];
        base[b] = t;
    }
}

// G (row-reduced, squared, masked) + S (masked, materialized). One WG per (b, ti, sj<=ti).
__global__ __launch_bounds__(256) void k_gs(const float* __restrict__ Q, const float* __restrict__ K,
                                            float* __restrict__ S, float* __restrict__ r2d,
                                            int L, int D, int nT, int nPairs) {
    int p = blockIdx.x % nPairs;
    int b = blockIdx.x / nPairs;
    int ti = (int)((sqrtf(8.f * p + 1.f) - 1.f) * 0.5f);
    while ((ti + 1) * (ti + 2) / 2 <= p) ti++;
    while (ti * (ti + 1) / 2 > p) ti--;
    int sj = p - ti * (ti + 1) / 2;

    const float* Qb = Q + (size_t)b * L * D;
    const float* Kb = K + (size_t)b * L * D;
    int t0 = ti * 64, s0 = sj * 64;

    __shared__ float lKt[32 * LDSPAD];  // transposed: [kk][t-row]
    __shared__ float lQt[32 * LDSPAD];
    __shared__ float lKs[32 * LDSPAD];  // transposed: [kk][s-row]

    int tid = threadIdx.x;
    int tx = tid & 15, ty = tid >> 4;
    float accG[4][4] = {}, accS[4][4] = {};

    for (int dc = 0; dc < D; dc += 32) {
        __syncthreads();
        for (int f = tid; f < 512; f += 256) {
            int r = f >> 3, c4 = (f & 7) * 4;
            float4 a = *(const float4*)(Kb + (size_t)(t0 + r) * D + dc + c4);
            float4 qq = *(const float4*)(Qb + (size_t)(t0 + r) * D + dc + c4);
            float4 bb = *(const float4*)(Kb + (size_t)(s0 + r) * D + dc + c4);
            lKt[(c4 + 0) * LDSPAD + r] = a.x;  lKt[(c4 + 1) * LDSPAD + r] = a.y;
            lKt[(c4 + 2) * LDSPAD + r] = a.z;  lKt[(c4 + 3) * LDSPAD + r] = a.w;
            lQt[(c4 + 0) * LDSPAD + r] = qq.x; lQt[(c4 + 1) * LDSPAD + r] = qq.y;
            lQt[(c4 + 2) * LDSPAD + r] = qq.z; lQt[(c4 + 3) * LDSPAD + r] = qq.w;
            lKs[(c4 + 0) * LDSPAD + r] = bb.x; lKs[(c4 + 1) * LDSPAD + r] = bb.y;
            lKs[(c4 + 2) * LDSPAD + r] = bb.z; lKs[(c4 + 3) * LDSPAD + r] = bb.w;
        }
        __syncthreads();
#pragma unroll 8
        for (int kk = 0; kk < 32; kk++) {
            float4 a = *(const float4*)&lKt[kk * LDSPAD + ty * 4];
            float4 qv = *(const float4*)&lQt[kk * LDSPAD + ty * 4];
            float4 bv = *(const float4*)&lKs[kk * LDSPAD + tx * 4];
            float av[4] = {a.x, a.y, a.z, a.w};
            float qa[4] = {qv.x, qv.y, qv.z, qv.w};
            float ba[4] = {bv.x, bv.y, bv.z, bv.w};
#pragma unroll
            for (int i = 0; i < 4; i++)
#pragma unroll
                for (int j = 0; j < 4; j++) {
                    accG[i][j] += av[i] * ba[j];
                    accS[i][j] += qa[i] * ba[j];
                }
        }
    }

    float* Sb = S + (size_t)b * L * L;
    float rsum[4];
#pragma unroll
    for (int i = 0; i < 4; i++) {
        int t = t0 + ty * 4 + i;
        float rs = 0.f, tmp[4];
#pragma unroll
        for (int j = 0; j < 4; j++) {
            int s = s0 + tx * 4 + j;
            float g = accG[i][j];
            float w = (s < t) ? 2.f : ((s == t) ? 1.f : 0.f);
            rs += w * g * g;
            tmp[j] = (s <= t) ? accS[i][j] : 0.f;
        }
        float4 so = {tmp[0], tmp[1], tmp[2], tmp[3]};
        *(float4*)(Sb + (size_t)t * L + s0 + tx * 4) = so;
        rsum[i] = rs;
    }
#pragma unroll
    for (int off = 1; off < 16; off <<= 1) {
#pragma unroll
        for (int i = 0; i < 4; i++) rsum[i] += __shfl_xor(rsum[i], off);
    }
    if (tx == 0) {
#pragma unroll
        for (int i = 0; i < 4; i++) {
            int t = t0 + ty * 4 + i;
            r2d[((size_t)b * L + t) * nT + sj] = rsum[i];
        }
    }
}

// prefix-scan r over t (deterministic), output invfro. One WG per batch; L == 4*blockDim.
__global__ __launch_bounds__(256) void k_scan(const float* __restrict__ K, const float* __restrict__ Pprev,
                                              const float* __restrict__ r2d, const float* __restrict__ base,
                                              float* __restrict__ invfro, int L, int D, int nT) {
    int b = blockIdx.x;
    int tid = threadIdx.x;
    float bb = base[b];
    float v[4];
#pragma unroll
    for (int u = 0; u < 4; u++) {
        int t = tid * 4 + u;
        float s = 0.f;
        int hi = t >> 6;
        for (int j = 0; j <= hi; j++) s += r2d[((size_t)b * L + t) * nT + j];
        if (bb != 0.f) {  // general Pprev path (skipped in this bench)
            const float* kt = K + ((size_t)b * L + t) * D;
            const float* P = Pprev + (size_t)b * D * D;
            float c = 0.f;
            for (int i = 0; i < D; i++) {
                float w = 0.f;
                for (int j2 = 0; j2 < D; j2++) w += P[i * D + j2] * kt[j2];
                c += kt[i] * w;
            }
            s += 2.f * c;
        }
        v[u] = s;
    }
    v[1] += v[0]; v[2] += v[1]; v[3] += v[2];
    float tot = v[3];
    int lane = tid & 63, wid = tid >> 6;
    float sc = tot;
    for (int off = 1; off < 64; off <<= 1) {
        float n = __shfl_up(sc, off);
        if (lane >= off) sc += n;
    }
    __shared__ float wsum[4];
    if (lane == 63) wsum[wid] = sc;
    __syncthreads();
    float woff = 0.f;
    for (int i = 0; i < wid; i++) woff += wsum[i];
    float exc = woff + sc - tot;
#pragma unroll
    for (int u = 0; u < 4; u++) {
        int t = tid * 4 + u;
        float fro2 = bb + exc + v[u];
        invfro[(size_t)b * L + t] = 1.f / (sqrtf(fro2) + 1e-7f);
    }
}

// Y = tril(S) @ K (+ Q Pprev^T), fused tanh epilogue -> q_out. One WG per (b, ti, dj).
__global__ __launch_bounds__(256) void k_y(const float* __restrict__ Q, const float* __restrict__ K,
                                           const float* __restrict__ Pprev, const float* __restrict__ S,
                                           const float* __restrict__ invfro, const float* __restrict__ base,
                                           const float* __restrict__ log_gain, const float* __restrict__ oscale,
                                           float* __restrict__ out, int L, int D, int nT) {
    int nD = D >> 6;
    int x = blockIdx.x;
    int dj = x % nD; x /= nD;
    int ti = x % nT;
    int b = x / nT;
    int t0 = ti * 64, d0 = dj * 64;
    const float* Kb = K + (size_t)b * L * D;
    const float* Sb = S + (size_t)b * L * L;

    __shared__ float lS[64 * LDSPAD];  // transposed: [s][t-row]
    __shared__ float lK[64 * LDSPAD];  // row-major: [s][d-col]

    int tid = threadIdx.x, tx = tid & 15, ty = tid >> 4;
    float acc[4][4] = {};

    for (int sj = 0; sj <= ti; sj++) {
        int s0 = sj * 64;
        __syncthreads();
        for (int f = tid; f < 1024; f += 256) {
            int r = f >> 4, c4 = (f & 15) * 4;
            float4 sv = *(const float4*)(Sb + (size_t)(t0 + r) * L + s0 + c4);
            lS[(c4 + 0) * LDSPAD + r] = sv.x; lS[(c4 + 1) * LDSPAD + r] = sv.y;
            lS[(c4 + 2) * LDSPAD + r] = sv.z; lS[(c4 + 3) * LDSPAD + r] = sv.w;
            float4 kv = *(const float4*)(Kb + (size_t)(s0 + r) * D + d0 + c4);
            *(float4*)&lK[r * LDSPAD + c4] = kv;
        }
        __syncthreads();
#pragma unroll 8
        for (int s = 0; s < 64; s++) {
            float4 sv = *(const float4*)&lS[s * LDSPAD + ty * 4];
            float4 kv = *(const float4*)&lK[s * LDSPAD + tx * 4];
            float sa[4] = {sv.x, sv.y, sv.z, sv.w};
            float ka[4] = {kv.x, kv.y, kv.z, kv.w};
#pragma unroll
            for (int i = 0; i < 4; i++)
#pragma unroll
                for (int j = 0; j < 4; j++) acc[i][j] += sa[i] * ka[j];
        }
    }

    if (base[b] != 0.f) {  // general Pprev path (skipped in this bench)
        const float* Pb = Pprev + (size_t)b * D * D;
        const float* Qb = Q + (size_t)b * L * D;
        for (int jj = 0; jj < D; jj++) {
            float pv[4], qv[4];
#pragma unroll
            for (int j = 0; j < 4; j++) pv[j] = Pb[(size_t)(d0 + tx * 4 + j) * D + jj];
#pragma unroll
            for (int i = 0; i < 4; i++) qv[i] = Qb[(size_t)(t0 + ty * 4 + i) * D + jj];
#pragma unroll
            for (int i = 0; i < 4; i++)
#pragma unroll
                for (int j = 0; j < 4; j++) acc[i][j] += qv[i] * pv[j];
        }
    }

    float gaind[4], osd[4];
#pragma unroll
    for (int j = 0; j < 4; j++) {
        int d = d0 + tx * 4 + j;
        gaind[j] = expf(log_gain[d]);
        osd[j] = oscale[d];
    }
#pragma unroll
    for (int i = 0; i < 4; i++) {
        int t = t0 + ty * 4 + i;
        float inv = invfro[(size_t)b * L + t];
        float tmp[4];
#pragma unroll
        for (int j = 0; j < 4; j++) tmp[j] = tanhf(gaind[j] * acc[i][j] * inv) * osd[j];
        float4 o = {tmp[0], tmp[1], tmp[2], tmp[3]};
        *(float4*)(out + ((size_t)b * L + t) * D + d0 + tx * 4) = o;
    }
}

// K^T K partials over 4 L-chunks. One WG per (b, ij-tile, lc).
__global__ __launch_bounds__(256) void k_p(const float* __restrict__ K, float* __restrict__ P4,
                                           int L, int D) {
    int nDj = D >> 6;
    int nIJ = nDj * nDj;
    int x = blockIdx.x;
    int lc = x & 3; x >>= 2;
    int ij = x % nIJ;
    int b = x / nIJ;
    int ib = (ij / nDj) * 64, jb = (ij % nDj) * 64;
    int tchunk = L >> 2;
    int tstart = lc * tchunk;
    const float* Kb = K + (size_t)b * L * D;

    __shared__ float lA[32 * LDSPAD];
    __shared__ float lB[32 * LDSPAD];
    int tid = threadIdx.x, tx = tid & 15, ty = tid >> 4;
    float acc[4][4] = {};

    for (int tc = 0; tc < tchunk; tc += 32) {
        __syncthreads();
        for (int f = tid; f < 512; f += 256) {
            int r = f >> 4, c4 = (f & 15) * 4;
            float4 av = *(const float4*)(Kb + (size_t)(tstart + tc + r) * D + ib + c4);
            *(float4*)&lA[r * LDSPAD + c4] = av;
            float4 bv = *(const float4*)(Kb + (size_t)(tstart + tc + r) * D + jb + c4);
            *(float4*)&lB[r * LDSPAD + c4] = bv;
        }
        __syncthreads();
#pragma unroll 8
        for (int t = 0; t < 32; t++) {
            float4 av = *(const float4*)&lA[t * LDSPAD + ty * 4];
            float4 bv = *(const float4*)&lB[t * LDSPAD + tx * 4];
            float aa[4] = {av.x, av.y, av.z, av.w};
            float ba[4] = {bv.x, bv.y, bv.z, bv.w};
#pragma unroll
            for (int i = 0; i < 4; i++)
#pragma unroll
                for (int j = 0; j < 4; j++) acc[i][j] += aa[i] * ba[j];
        }
    }
    float* dst = P4 + ((((size_t)b * nIJ + ij) * 4 + lc) * 4096);
#pragma unroll
    for (int i = 0; i < 4; i++) {
        float4 o = {acc[i][0], acc[i][1], acc[i][2], acc[i][3]};
        *(float4*)(dst + (ty * 4 + i) * 64 + tx * 4) = o;
    }
}

__global__ void k_pred(const float* __restrict__ Pprev, const float* __restrict__ P4,
                       float* __restrict__ outP, int B, int D) {
    int nDj = D >> 6;
    int nIJ = nDj * nDj;
    size_t e4 = (size_t)blockIdx.x * blockDim.x + threadIdx.x;
    size_t n4 = (size_t)B * D * D / 4;
    if (e4 >= n4) return;
    size_t e = e4 * 4;
    int b = (int)(e / ((size_t)D * D));
    int rem = (int)(e % ((size_t)D * D));
    int i = rem / D, j = rem % D;
    int ij = (i >> 6) * nDj + (j >> 6);
    int li = i & 63, lj = j & 63;
    const float* src = P4 + ((size_t)b * nIJ + ij) * 4 * 4096 + li * 64 + lj;
    float4 pp = *(const float4*)(Pprev + e);
    float4 a0 = *(const float4*)(src + 0 * 4096);
    float4 a1 = *(const float4*)(src + 1 * 4096);
    float4 a2 = *(const float4*)(src + 2 * 4096);
    float4 a3 = *(const float4*)(src + 3 * 4096);
    float4 o;
    o.x = pp.x + a0.x + a1.x + a2.x + a3.x;
    o.y = pp.y + a0.y + a1.y + a2.y + a3.y;
    o.z = pp.z + a0.z + a1.z + a2.z + a3.z;
    o.w = pp.w + a0.w + a1.w + a2.w + a3.w;
    *(float4*)(outP + e) = o;
}

extern "C" void kernel_launch(void* const* d_in, const int* in_sizes, int n_in,
                              void* d_out, int out_size, void* d_ws, size_t ws_size,
                              hipStream_t stream) {
    const float* q = (const float*)d_in[0];
    const float* k = (const float*)d_in[1];
    const float* Pprev = (const float*)d_in[2];
    const float* log_gain = (const float*)d_in[3];
    const float* oscale = (const float*)d_in[4];

    int D = in_sizes[3];                 // 256
    int B = in_sizes[2] / (D * D);       // 4
    int L = in_sizes[0] / (B * D);       // 1024
    int nT = L / 64;                     // 16
    int nPairs = nT * (nT + 1) / 2;      // 136
    int nDj = D >> 6;                    // 4
    int nIJ = nDj * nDj;                 // 16

    float* out = (float*)d_out;
    float* outP = out + (size_t)B * L * D;

    size_t sS = (size_t)B * L * L;
    size_t sR = (size_t)B * L * nT;
    size_t sI = (size_t)B * L;
    size_t sBase = 16;
    size_t sP4 = (size_t)B * nIJ * 4 * 4096;
    size_t need = (sS + sR + sI + sBase + sP4) * sizeof(float);
    if (ws_size < need) return;  // insufficient scratch -> fail validation loudly

    float* wsf = (float*)d_ws;
    float* S = wsf;
    float* r2d = S + sS;
    float* invfro = r2d + sR;
    float* base = invfro + sI;
    float* P4 = base + sBase;

    k_base<<<B, 256, 0, stream>>>(Pprev, base, D);
    k_gs<<<B * nPairs, 256, 0, stream>>>(q, k, S, r2d, L, D, nT, nPairs);
    k_scan<<<B, 256, 0, stream>>>(k, Pprev, r2d, base, invfro, L, D, nT);
    k_y<<<B * nT * nDj, 256, 0, stream>>>(q, k, Pprev, S, invfro, base, log_gain, oscale,
                                          out, L, D, nT);
    k_p<<<B * nIJ * 4, 256, 0, stream>>>(k, P4, L, D);
    k_pred<<<(int)(((size_t)B * D * D / 4 + 255) / 256), 256, 0, stream>>>(Pprev, P4, outP, B, D);
}

// Round 3
// 142.619 us; speedup vs baseline: 1.1096x; 1.1096x over previous
//
#include <hip/hip_runtime.h>
#include <math.h>

// QK projection layer: scan -> GEMM reformulation.
//   S = Q K^T (causal-masked, bf16 in ws)
//   r_t = 2*sum_{s<t} G[t][s]^2 + G[t][t]^2 (+ 2 k^T Pprev k if Pprev != 0), G = K K^T
//   fro2[t] = ||Pprev||^2 + prefix(r)  -> invfro
//   Y = tril(S) @ K, pair-parallel partials (bf16) + reduce with fused tanh epilogue
//   P_final = Pprev + K^T K  (pure fp32 path)

#define LDSPAD 68   // only used by k_p (row-major float4 staging, conflict-benign)
#define NC 4        // sj-chunks for Y partials

// ---- bf16 helpers (bit-level, RNE) ----
__device__ __forceinline__ float bflo(unsigned u) {
    union { unsigned u; float f; } c; c.u = u << 16; return c.f;
}
__device__ __forceinline__ float bfhi(unsigned u) {
    union { unsigned u; float f; } c; c.u = u & 0xffff0000u; return c.f;
}
__device__ __forceinline__ unsigned f2bf2(float a, float b) {  // pack two, RNE
    union { float f; unsigned u; } ca, cb; ca.f = a; cb.f = b;
    unsigned ua = ca.u; ua += 0x7fffu + ((ua >> 16) & 1u);
    unsigned ub = cb.u; ub += 0x7fffu + ((ub >> 16) & 1u);
    return (ua >> 16) | (ub & 0xffff0000u);
}

// swizzled addr for transposed [rows][64] fp32 tiles: element (row, col) lives at
// row*64 + ((((col>>2) ^ (row>>2)) & 15) << 2) + (col & 3); float4-read granule q
// of row r is at r*64 + (((q ^ (r>>2)) & 15) << 2).
#define SWW(rr, cc) (((((cc) >> 2) ^ ((rr) >> 2)) & 15) << 2 | ((cc) & 3))
#define SWR(rr, q)  ((((q) ^ ((rr) >> 2)) & 15) << 2)

__global__ void k_base(const float* __restrict__ Pprev, float* __restrict__ base, int D) {
    int b = blockIdx.x;
    const float* P = Pprev + (size_t)b * D * D;
    int n = D * D;
    float s = 0.f;
    for (int i = threadIdx.x * 4; i < n; i += blockDim.x * 4) {
        float4 v = *(const float4*)(P + i);
        s += v.x * v.x + v.y * v.y + v.z * v.z + v.w * v.w;
    }
    for (int off = 32; off; off >>= 1) s += __shfl_down(s, off);
    __shared__ float wsum[8];
    int wid = threadIdx.x >> 6, lane = threadIdx.x & 63;
    if (lane == 0) wsum[wid] = s;
    __syncthreads();
    if (threadIdx.x == 0) {
        float t = 0.f;
        int nw = blockDim.x >> 6;
        for (int i = 0; i < nw; i++) t += wsum[i];
        base[b] = t;
    }
}

// G (row-reduced, squared, masked) + S (masked, bf16). One WG per (b, ti, sj<=ti).
__global__ __launch_bounds__(256) void k_gs(const float* __restrict__ Q, const float* __restrict__ K,
                                            unsigned short* __restrict__ S16, float* __restrict__ r2d,
                                            int L, int D, int nT, int nPairs) {
    int p = blockIdx.x % nPairs;
    int b = blockIdx.x / nPairs;
    int ti = (int)((sqrtf(8.f * p + 1.f) - 1.f) * 0.5f);
    while ((ti + 1) * (ti + 2) / 2 <= p) ti++;
    while (ti * (ti + 1) / 2 > p) ti--;
    int sj = p - ti * (ti + 1) / 2;

    const float* Qb = Q + (size_t)b * L * D;
    const float* Kb = K + (size_t)b * L * D;
    int t0 = ti * 64, s0 = sj * 64;

    __shared__ float lKt[32 * 64];  // [kk][t-row], swizzled
    __shared__ float lQt[32 * 64];
    __shared__ float lKs[32 * 64];  // [kk][s-row], swizzled

    int tid = threadIdx.x;
    int tx = tid & 15, ty = tid >> 4;
    float accG[4][4] = {}, accS[4][4] = {};

    for (int dc = 0; dc < D; dc += 32) {
        __syncthreads();
        for (int f = tid; f < 512; f += 256) {
            int r = f >> 3, c4 = (f & 7) * 4;
            float4 a = *(const float4*)(Kb + (size_t)(t0 + r) * D + dc + c4);
            float4 qq = *(const float4*)(Qb + (size_t)(t0 + r) * D + dc + c4);
            float4 bb = *(const float4*)(Kb + (size_t)(s0 + r) * D + dc + c4);
            float av[4] = {a.x, a.y, a.z, a.w};
            float qa[4] = {qq.x, qq.y, qq.z, qq.w};
            float bv[4] = {bb.x, bb.y, bb.z, bb.w};
#pragma unroll
            for (int i = 0; i < 4; i++) {
                int kk = c4 + i;
                int sw = kk * 64 + SWW(kk, r);
                lKt[sw] = av[i];
                lQt[sw] = qa[i];
                lKs[sw] = bv[i];
            }
        }
        __syncthreads();
#pragma unroll 4
        for (int kk = 0; kk < 32; kk++) {
            float4 a = *(const float4*)&lKt[kk * 64 + SWR(kk, ty)];
            float4 qv = *(const float4*)&lQt[kk * 64 + SWR(kk, ty)];
            float4 bv = *(const float4*)&lKs[kk * 64 + SWR(kk, tx)];
            float av[4] = {a.x, a.y, a.z, a.w};
            float qa[4] = {qv.x, qv.y, qv.z, qv.w};
            float ba[4] = {bv.x, bv.y, bv.z, bv.w};
#pragma unroll
            for (int i = 0; i < 4; i++)
#pragma unroll
                for (int j = 0; j < 4; j++) {
                    accG[i][j] += av[i] * ba[j];
                    accS[i][j] += qa[i] * ba[j];
                }
        }
    }

    unsigned short* Sb = S16 + (size_t)b * L * L;
    float rsum[4];
#pragma unroll
    for (int i = 0; i < 4; i++) {
        int t = t0 + ty * 4 + i;
        float rs = 0.f, tmp[4];
#pragma unroll
        for (int j = 0; j < 4; j++) {
            int s = s0 + tx * 4 + j;
            float g = accG[i][j];
            float w = (s < t) ? 2.f : ((s == t) ? 1.f : 0.f);
            rs += w * g * g;
            tmp[j] = (s <= t) ? accS[i][j] : 0.f;
        }
        uint2 so;
        so.x = f2bf2(tmp[0], tmp[1]);
        so.y = f2bf2(tmp[2], tmp[3]);
        *(uint2*)(Sb + (size_t)t * L + s0 + tx * 4) = so;
        rsum[i] = rs;
    }
#pragma unroll
    for (int off = 1; off < 16; off <<= 1) {
#pragma unroll
        for (int i = 0; i < 4; i++) rsum[i] += __shfl_xor(rsum[i], off);
    }
    if (tx == 0) {
#pragma unroll
        for (int i = 0; i < 4; i++) {
            int t = t0 + ty * 4 + i;
            r2d[((size_t)b * L + t) * nT + sj] = rsum[i];
        }
    }
}

// prefix-scan r over t (deterministic), output invfro. One WG per batch; L == 4*blockDim.
__global__ __launch_bounds__(256) void k_scan(const float* __restrict__ K, const float* __restrict__ Pprev,
                                              const float* __restrict__ r2d, const float* __restrict__ base,
                                              float* __restrict__ invfro, int L, int D, int nT) {
    int b = blockIdx.x;
    int tid = threadIdx.x;
    float bb = base[b];
    float v[4];
#pragma unroll
    for (int u = 0; u < 4; u++) {
        int t = tid * 4 + u;
        float s = 0.f;
        int hi = t >> 6;
        for (int j = 0; j <= hi; j++) s += r2d[((size_t)b * L + t) * nT + j];
        if (bb != 0.f) {  // general Pprev path (skipped in this bench)
            const float* kt = K + ((size_t)b * L + t) * D;
            const float* P = Pprev + (size_t)b * D * D;
            float c = 0.f;
            for (int i = 0; i < D; i++) {
                float w = 0.f;
                for (int j2 = 0; j2 < D; j2++) w += P[i * D + j2] * kt[j2];
                c += kt[i] * w;
            }
            s += 2.f * c;
        }
        v[u] = s;
    }
    v[1] += v[0]; v[2] += v[1]; v[3] += v[2];
    float tot = v[3];
    int lane = tid & 63, wid = tid >> 6;
    float sc = tot;
    for (int off = 1; off < 64; off <<= 1) {
        float n = __shfl_up(sc, off);
        if (lane >= off) sc += n;
    }
    __shared__ float wsum[4];
    if (lane == 63) wsum[wid] = sc;
    __syncthreads();
    float woff = 0.f;
    for (int i = 0; i < wid; i++) woff += wsum[i];
    float exc = woff + sc - tot;
#pragma unroll
    for (int u = 0; u < 4; u++) {
        int t = tid * 4 + u;
        float fro2 = bb + exc + v[u];
        invfro[(size_t)b * L + t] = 1.f / (sqrtf(fro2) + 1e-7f);
    }
}

// Y partials: one WG per (b, ti, dj, c); handles sj in {c, c+NC, ...} <= ti.
// Writes 64x64 bf16 partial per WG slot.
__global__ __launch_bounds__(256) void k_ypart(const unsigned short* __restrict__ S16,
                                               const float* __restrict__ K,
                                               unsigned short* __restrict__ Ypart,
                                               int L, int D, int nT) {
    int nDj = D >> 6;
    int x = blockIdx.x;
    int c = x & (NC - 1); x >>= 2;
    int dj = x % nDj; x /= nDj;
    int ti = x % nT;
    int b = x / nT;
    if (c > ti) return;  // empty chunk; k_yred skips it

    int t0 = ti * 64, d0 = dj * 64;
    const unsigned short* Sb = S16 + (size_t)b * L * L;
    const float* Kb = K + (size_t)b * L * D;

    __shared__ float lS[64 * 64];  // [s][t], swizzled
    __shared__ float lK[64 * 64];  // [s][d], row-major

    int tid = threadIdx.x, tx = tid & 15, ty = tid >> 4;
    float acc[4][4] = {};

    for (int sj = c; sj <= ti; sj += NC) {
        int s0 = sj * 64;
        __syncthreads();
        // stage S tile (bf16 -> fp32, transposed+swizzled)
        for (int f = tid; f < 512; f += 256) {
            int r = f >> 3, c8 = (f & 7) * 8;
            uint4 sv = *(const uint4*)(Sb + (size_t)(t0 + r) * L + s0 + c8);
            float s8[8] = {bflo(sv.x), bfhi(sv.x), bflo(sv.y), bfhi(sv.y),
                           bflo(sv.z), bfhi(sv.z), bflo(sv.w), bfhi(sv.w)};
#pragma unroll
            for (int jj = 0; jj < 8; jj++) {
                int s = c8 + jj;
                lS[s * 64 + SWW(s, r)] = s8[jj];
            }
        }
        // stage K tile (fp32 row-major)
        for (int f = tid; f < 1024; f += 256) {
            int r = f >> 4, c4 = (f & 15) * 4;
            float4 kv = *(const float4*)(Kb + (size_t)(s0 + r) * D + d0 + c4);
            *(float4*)&lK[r * 64 + c4] = kv;
        }
        __syncthreads();
#pragma unroll 4
        for (int s4 = 0; s4 < 16; s4++) {
            int swt = ((ty ^ s4) & 15) << 2;
#pragma unroll
            for (int u = 0; u < 4; u++) {
                int s = s4 * 4 + u;
                float4 sv = *(const float4*)&lS[s * 64 + swt];
                float4 kv = *(const float4*)&lK[s * 64 + (tx << 2)];
                float sa[4] = {sv.x, sv.y, sv.z, sv.w};
                float ka[4] = {kv.x, kv.y, kv.z, kv.w};
#pragma unroll
                for (int i = 0; i < 4; i++)
#pragma unroll
                    for (int j = 0; j < 4; j++) acc[i][j] += sa[i] * ka[j];
            }
        }
    }

    unsigned short* dst = Ypart +
        ((((size_t)(b * nT + ti) * nDj + dj) * NC + c) << 12);
#pragma unroll
    for (int i = 0; i < 4; i++) {
        uint2 o;
        o.x = f2bf2(acc[i][0], acc[i][1]);
        o.y = f2bf2(acc[i][2], acc[i][3]);
        *(uint2*)(dst + (ty * 4 + i) * 64 + tx * 4) = o;
    }
}

// Reduce Y partials + fused epilogue: q_out = tanh(gain * Y * invfro) * oscale.
__global__ __launch_bounds__(256) void k_yred(const unsigned short* __restrict__ Ypart,
                                              const float* __restrict__ Q, const float* __restrict__ Pprev,
                                              const float* __restrict__ invfro, const float* __restrict__ base,
                                              const float* __restrict__ log_gain, const float* __restrict__ oscale,
                                              float* __restrict__ out, int L, int D, int nT) {
    int nDj = D >> 6;
    size_t e = ((size_t)blockIdx.x * blockDim.x + threadIdx.x) * 8;
    int b = (int)(e / ((size_t)L * D));
    int rem = (int)(e % ((size_t)L * D));
    int t = rem / D, d = rem % D;
    int ti = t >> 6, dj = d >> 6;
    int nv = ti + 1 < NC ? ti + 1 : NC;

    const unsigned short* pp = Ypart +
        (((size_t)(b * nT + ti) * nDj + dj) << 2 << 12) + (t & 63) * 64 + (d & 63);
    float a[8] = {};
    for (int cc = 0; cc < nv; cc++) {
        uint4 v = *(const uint4*)(pp + (cc << 12));
        a[0] += bflo(v.x); a[1] += bfhi(v.x);
        a[2] += bflo(v.y); a[3] += bfhi(v.y);
        a[4] += bflo(v.z); a[5] += bfhi(v.z);
        a[6] += bflo(v.w); a[7] += bfhi(v.w);
    }
    if (base[b] != 0.f) {  // general Pprev path (skipped in this bench)
        const float* Qt = Q + ((size_t)b * L + t) * D;
        const float* Pb = Pprev + (size_t)b * D * D;
        for (int jj = 0; jj < D; jj++) {
            float qv = Qt[jj];
#pragma unroll
            for (int j = 0; j < 8; j++) a[j] += qv * Pb[(size_t)(d + j) * D + jj];
        }
    }
    float inv = invfro[(size_t)b * L + t];
    float o[8];
#pragma unroll
    for (int j = 0; j < 8; j++)
        o[j] = tanhf(expf(log_gain[d + j]) * a[j] * inv) * oscale[d + j];
    float4 o0 = {o[0], o[1], o[2], o[3]};
    float4 o1 = {o[4], o[5], o[6], o[7]};
    *(float4*)(out + e) = o0;
    *(float4*)(out + e + 4) = o1;
}

// K^T K partials over 4 L-chunks. One WG per (b, ij-tile, lc).
__global__ __launch_bounds__(256) void k_p(const float* __restrict__ K, float* __restrict__ P4,
                                           int L, int D) {
    int nDj = D >> 6;
    int nIJ = nDj * nDj;
    int x = blockIdx.x;
    int lc = x & 3; x >>= 2;
    int ij = x % nIJ;
    int b = x / nIJ;
    int ib = (ij / nDj) * 64, jb = (ij % nDj) * 64;
    int tchunk = L >> 2;
    int tstart = lc * tchunk;
    const float* Kb = K + (size_t)b * L * D;

    __shared__ float lA[32 * LDSPAD];
    __shared__ float lB[32 * LDSPAD];
    int tid = threadIdx.x, tx = tid & 15, ty = tid >> 4;
    float acc[4][4] = {};

    for (int tc = 0; tc < tchunk; tc += 32) {
        __syncthreads();
        for (int f = tid; f < 512; f += 256) {
            int r = f >> 4, c4 = (f & 15) * 4;
            float4 av = *(const float4*)(Kb + (size_t)(tstart + tc + r) * D + ib + c4);
            *(float4*)&lA[r * LDSPAD + c4] = av;
            float4 bv = *(const float4*)(Kb + (size_t)(tstart + tc + r) * D + jb + c4);
            *(float4*)&lB[r * LDSPAD + c4] = bv;
        }
        __syncthreads();
#pragma unroll 8
        for (int t = 0; t < 32; t++) {
            float4 av = *(const float4*)&lA[t * LDSPAD + ty * 4];
            float4 bv = *(const float4*)&lB[t * LDSPAD + tx * 4];
            float aa[4] = {av.x, av.y, av.z, av.w};
            float ba[4] = {bv.x, bv.y, bv.z, bv.w};
#pragma unroll
            for (int i = 0; i < 4; i++)
#pragma unroll
                for (int j = 0; j < 4; j++) acc[i][j] += aa[i] * ba[j];
        }
    }
    float* dst = P4 + ((((size_t)b * nIJ + ij) * 4 + lc) * 4096);
#pragma unroll
    for (int i = 0; i < 4; i++) {
        float4 o = {acc[i][0], acc[i][1], acc[i][2], acc[i][3]};
        *(float4*)(dst + (ty * 4 + i) * 64 + tx * 4) = o;
    }
}

__global__ void k_pred(const float* __restrict__ Pprev, const float* __restrict__ P4,
                       float* __restrict__ outP, int B, int D) {
    int nDj = D >> 6;
    int nIJ = nDj * nDj;
    size_t e4 = (size_t)blockIdx.x * blockDim.x + threadIdx.x;
    size_t n4 = (size_t)B * D * D / 4;
    if (e4 >= n4) return;
    size_t e = e4 * 4;
    int b = (int)(e / ((size_t)D * D));
    int rem = (int)(e % ((size_t)D * D));
    int i = rem / D, j = rem % D;
    int ij = (i >> 6) * nDj + (j >> 6);
    int li = i & 63, lj = j & 63;
    const float* src = P4 + ((size_t)b * nIJ + ij) * 4 * 4096 + li * 64 + lj;
    float4 pp = *(const float4*)(Pprev + e);
    float4 a0 = *(const float4*)(src + 0 * 4096);
    float4 a1 = *(const float4*)(src + 1 * 4096);
    float4 a2 = *(const float4*)(src + 2 * 4096);
    float4 a3 = *(const float4*)(src + 3 * 4096);
    float4 o;
    o.x = pp.x + a0.x + a1.x + a2.x + a3.x;
    o.y = pp.y + a0.y + a1.y + a2.y + a3.y;
    o.z = pp.z + a0.z + a1.z + a2.z + a3.z;
    o.w = pp.w + a0.w + a1.w + a2.w + a3.w;
    *(float4*)(outP + e) = o;
}

extern "C" void kernel_launch(void* const* d_in, const int* in_sizes, int n_in,
                              void* d_out, int out_size, void* d_ws, size_t ws_size,
                              hipStream_t stream) {
    const float* q = (const float*)d_in[0];
    const float* k = (const float*)d_in[1];
    const float* Pprev = (const float*)d_in[2];
    const float* log_gain = (const float*)d_in[3];
    const float* oscale = (const float*)d_in[4];

    int D = in_sizes[3];                 // 256
    int B = in_sizes[2] / (D * D);       // 4
    int L = in_sizes[0] / (B * D);       // 1024
    int nT = L / 64;                     // 16
    int nPairs = nT * (nT + 1) / 2;      // 136
    int nDj = D >> 6;                    // 4
    int nIJ = nDj * nDj;                 // 16

    float* out = (float*)d_out;
    float* outP = out + (size_t)B * L * D;

    size_t sS_b = (size_t)B * L * L * 2;            // bf16 S
    size_t sR = (size_t)B * L * nT;                 // fp32
    size_t sI = (size_t)B * L;
    size_t sBase = 16;
    size_t sP4 = (size_t)B * nIJ * 4 * 4096;        // fp32
    size_t sYp_b = (size_t)B * nT * nDj * NC * 4096 * 2;  // bf16 partials
    size_t need = sS_b + (sR + sI + sBase + sP4) * sizeof(float) + sYp_b;
    if (ws_size < need) return;  // insufficient scratch -> fail validation loudly

    char* w = (char*)d_ws;
    unsigned short* S16 = (unsigned short*)w;
    float* r2d = (float*)(w + sS_b);
    float* invfro = r2d + sR;
    float* base = invfro + sI;
    float* P4 = base + sBase;
    unsigned short* Ypart = (unsigned short*)(P4 + sP4);

    k_base<<<B, 256, 0, stream>>>(Pprev, base, D);
    k_gs<<<B * nPairs, 256, 0, stream>>>(q, k, S16, r2d, L, D, nT, nPairs);
    k_scan<<<B, 256, 0, stream>>>(k, Pprev, r2d, base, invfro, L, D, nT);
    k_ypart<<<B * nT * nDj * NC, 256, 0, stream>>>(S16, k, Ypart, L, D, nT);
    k_yred<<<(int)(((size_t)B * L * D / 8 + 255) / 256), 256, 0, stream>>>(
        Ypart, q, Pprev, invfro, base, log_gain, oscale, out, L, D, nT);
    k_p<<<B * nIJ * 4, 256, 0, stream>>>(k, P4, L, D);
    k_pred<<<(int)(((size_t)B * D * D / 4 + 255) / 256), 256, 0, stream>>>(Pprev, P4, outP, B, D);
}

// Round 4
// 103.595 us; speedup vs baseline: 1.5276x; 1.3767x over previous
//
#include <hip/hip_runtime.h>
#include <math.h>

// QK projection layer: scan -> GEMM reformulation, bf16 MFMA for the L^2*D GEMMs.
//   k_cvt : q,k fp32 -> Qb16/Kb16 [B,L,D] bf16 + KT16 [B,D,L] bf16 (tiled transpose)
//   k_gs  : G=K K^T (row-reduced w*G^2 -> r2d) + S=Q K^T (causal, compact bf16) via MFMA
//   k_scan: fro2[t] = ||Pprev||^2 + prefix(r) -> invfro
//   k_y2  : Y = tril(S) @ K via MFMA (S x KT), fused tanh epilogue -> q_out
//   k_p   : P_final = Pprev + K^T K, pure fp32 (precision: bf16 would give ~0.3 abs on diag)

#define LDSPAD 68  // k_p fp32 staging stride

typedef __attribute__((ext_vector_type(8))) short bf16x8;
typedef __attribute__((ext_vector_type(4))) float f32x4;

__device__ __forceinline__ unsigned short f2bf(float x) {
    union { float f; unsigned u; } c; c.f = x;
    unsigned u = c.u + (0x7fffu + ((c.u >> 16) & 1u));
    return (unsigned short)(u >> 16);
}
__device__ __forceinline__ unsigned f2bf2(float a, float b) {  // low=a, high=b, RNE
    union { float f; unsigned u; } ca, cb; ca.f = a; cb.f = b;
    unsigned ua = ca.u + (0x7fffu + ((ca.u >> 16) & 1u));
    unsigned ub = cb.u + (0x7fffu + ((cb.u >> 16) & 1u));
    return (ua >> 16) | (ub & 0xffff0000u);
}

// MFMA fragment load: lane l reads 8 contiguous bf16 at row (l&15), k-offset (l>>4)*8
// of a row-major [16][K] tile (B-operand comes from B^T-storage rows the same way).
__device__ __forceinline__ bf16x8 ldfrag(const unsigned short* base, int stride) {
    int l = threadIdx.x & 63;
    return *(const bf16x8*)(base + (size_t)(l & 15) * stride + ((l >> 4) << 3));
}

// ---- convert + transpose: Qb16, Kb16 row-major; KT16 = K^T per batch ----
__global__ __launch_bounds__(256) void k_cvt(const float* __restrict__ Q, const float* __restrict__ K,
                                             unsigned short* __restrict__ Qb, unsigned short* __restrict__ Kb,
                                             unsigned short* __restrict__ KT, int L, int D) {
    int nDt = D >> 6, nLt = L >> 6;
    int x = blockIdx.x;
    int dt = x % nDt; x /= nDt;
    int lt = x % nLt; int b = x / nLt;
    const float* Qp = Q + (size_t)b * L * D;
    const float* Kp = K + (size_t)b * L * D;
    unsigned short* Qbp = Qb + (size_t)b * L * D;
    unsigned short* Kbp = Kb + (size_t)b * L * D;
    unsigned short* KTp = KT + (size_t)b * D * L;
    int l0 = lt * 64, d0 = dt * 64;
    __shared__ float lds[64 * 65];
    int tid = threadIdx.x;
    int r = tid >> 2, cq = (tid & 3) * 16;
#pragma unroll
    for (int i = 0; i < 16; i += 4) {
        float4 qv = *(const float4*)(Qp + (size_t)(l0 + r) * D + d0 + cq + i);
        float4 kv = *(const float4*)(Kp + (size_t)(l0 + r) * D + d0 + cq + i);
        uint2 qo, ko;
        qo.x = f2bf2(qv.x, qv.y); qo.y = f2bf2(qv.z, qv.w);
        ko.x = f2bf2(kv.x, kv.y); ko.y = f2bf2(kv.z, kv.w);
        *(uint2*)(Qbp + (size_t)(l0 + r) * D + d0 + cq + i) = qo;
        *(uint2*)(Kbp + (size_t)(l0 + r) * D + d0 + cq + i) = ko;
        lds[r * 65 + cq + i] = kv.x;     lds[r * 65 + cq + i + 1] = kv.y;
        lds[r * 65 + cq + i + 2] = kv.z; lds[r * 65 + cq + i + 3] = kv.w;
    }
    __syncthreads();
    int d = tid >> 2, cl = (tid & 3) * 16;
#pragma unroll
    for (int i = 0; i < 16; i += 4) {
        uint2 o;
        o.x = f2bf2(lds[(cl + i) * 65 + d], lds[(cl + i + 1) * 65 + d]);
        o.y = f2bf2(lds[(cl + i + 2) * 65 + d], lds[(cl + i + 3) * 65 + d]);
        *(uint2*)(KTp + (size_t)(d0 + d) * L + l0 + cl + i) = o;
    }
}

__global__ void k_base(const float* __restrict__ Pprev, float* __restrict__ base, int D) {
    int b = blockIdx.x;
    const float* P = Pprev + (size_t)b * D * D;
    int n = D * D;
    float s = 0.f;
    for (int i = threadIdx.x * 4; i < n; i += blockDim.x * 4) {
        float4 v = *(const float4*)(P + i);
        s += v.x * v.x + v.y * v.y + v.z * v.z + v.w * v.w;
    }
    for (int off = 32; off; off >>= 1) s += __shfl_down(s, off);
    __shared__ float wsum[8];
    int wid = threadIdx.x >> 6, lane = threadIdx.x & 63;
    if (lane == 0) wsum[wid] = s;
    __syncthreads();
    if (threadIdx.x == 0) {
        float t = 0.f;
        int nw = blockDim.x >> 6;
        for (int i = 0; i < nw; i++) t += wsum[i];
        base[b] = t;
    }
}

// ---- G + S via MFMA. One WG (4 waves, 2x2 of 32x32 quads) per (b, ti, sj<=ti). ----
__global__ __launch_bounds__(256) void k_gs(const unsigned short* __restrict__ Qb,
                                            const unsigned short* __restrict__ Kb,
                                            unsigned short* __restrict__ Sc, float* __restrict__ r2d,
                                            int L, int D, int nT, int nPairs) {
    int p = blockIdx.x % nPairs;
    int b = blockIdx.x / nPairs;
    int ti = (int)((sqrtf(8.f * p + 1.f) - 1.f) * 0.5f);
    while ((ti + 1) * (ti + 2) / 2 <= p) ti++;
    while (ti * (ti + 1) / 2 > p) ti--;
    int sj = p - ti * (ti + 1) / 2;

    const unsigned short* Qp = Qb + (size_t)b * L * D;
    const unsigned short* Kp = Kb + (size_t)b * L * D;
    int w = threadIdx.x >> 6, lane = threadIdx.x & 63;
    int wr = w >> 1, wc = w & 1;
    int tw = ti * 64 + wr * 32, sw = sj * 64 + wc * 32;
    int fr = lane & 15, fq = lane >> 4;

    f32x4 accG00 = {0,0,0,0}, accG01 = {0,0,0,0}, accG10 = {0,0,0,0}, accG11 = {0,0,0,0};
    f32x4 accS00 = {0,0,0,0}, accS01 = {0,0,0,0}, accS10 = {0,0,0,0}, accS11 = {0,0,0,0};

    for (int dc = 0; dc < D; dc += 32) {
        bf16x8 aK0 = ldfrag(Kp + (size_t)tw * D + dc, D);
        bf16x8 aK1 = ldfrag(Kp + (size_t)(tw + 16) * D + dc, D);
        bf16x8 aQ0 = ldfrag(Qp + (size_t)tw * D + dc, D);
        bf16x8 aQ1 = ldfrag(Qp + (size_t)(tw + 16) * D + dc, D);
        bf16x8 bK0 = ldfrag(Kp + (size_t)sw * D + dc, D);
        bf16x8 bK1 = ldfrag(Kp + (size_t)(sw + 16) * D + dc, D);
        accG00 = __builtin_amdgcn_mfma_f32_16x16x32_bf16(aK0, bK0, accG00, 0, 0, 0);
        accG01 = __builtin_amdgcn_mfma_f32_16x16x32_bf16(aK0, bK1, accG01, 0, 0, 0);
        accG10 = __builtin_amdgcn_mfma_f32_16x16x32_bf16(aK1, bK0, accG10, 0, 0, 0);
        accG11 = __builtin_amdgcn_mfma_f32_16x16x32_bf16(aK1, bK1, accG11, 0, 0, 0);
        accS00 = __builtin_amdgcn_mfma_f32_16x16x32_bf16(aQ0, bK0, accS00, 0, 0, 0);
        accS01 = __builtin_amdgcn_mfma_f32_16x16x32_bf16(aQ0, bK1, accS01, 0, 0, 0);
        accS10 = __builtin_amdgcn_mfma_f32_16x16x32_bf16(aQ1, bK0, accS10, 0, 0, 0);
        accS11 = __builtin_amdgcn_mfma_f32_16x16x32_bf16(aQ1, bK1, accS11, 0, 0, 0);
    }

    unsigned short* ScT = Sc + ((size_t)(b * nPairs + p) << 12);  // compact 64x64 tile
    float rsv[2][4] = {{0, 0, 0, 0}, {0, 0, 0, 0}};
    // C/D layout: col = lane&15 (s), row = (lane>>4)*4 + reg (t)  [m89/m91 verified]
#define EPI(MI, NI, AG, AS) { _Pragma("unroll") \
    for (int reg = 0; reg < 4; reg++) { \
        int tl = wr * 32 + MI * 16 + fq * 4 + reg; \
        int sl = wc * 32 + NI * 16 + fr; \
        int t = ti * 64 + tl, s = sj * 64 + sl; \
        float g = AG[reg]; \
        float wgt = (s < t) ? 2.f : (s == t ? 1.f : 0.f); \
        rsv[MI][reg] += wgt * g * g; \
        float sv = (s <= t) ? AS[reg] : 0.f; \
        ScT[tl * 64 + sl] = f2bf(sv); \
    } }
    EPI(0, 0, accG00, accS00) EPI(0, 1, accG01, accS01)
    EPI(1, 0, accG10, accS10) EPI(1, 1, accG11, accS11)
#undef EPI
#pragma unroll
    for (int off = 1; off < 16; off <<= 1) {
#pragma unroll
        for (int mi = 0; mi < 2; mi++)
#pragma unroll
            for (int reg = 0; reg < 4; reg++)
                rsv[mi][reg] += __shfl_xor(rsv[mi][reg], off);
    }
    if (fr == 0) {
#pragma unroll
        for (int mi = 0; mi < 2; mi++)
#pragma unroll
            for (int reg = 0; reg < 4; reg++) {
                int t = tw + mi * 16 + fq * 4 + reg;
                r2d[((size_t)b * L + t) * (2 * nT) + sj * 2 + wc] = rsv[mi][reg];
            }
    }
}

// prefix-scan r over t (deterministic), output invfro. One WG per batch; L == 4*blockDim.
__global__ __launch_bounds__(256) void k_scan(const float* __restrict__ K, const float* __restrict__ Pprev,
                                              const float* __restrict__ r2d, const float* __restrict__ base,
                                              float* __restrict__ invfro, int L, int D, int nT) {
    int b = blockIdx.x;
    int tid = threadIdx.x;
    float bb = base[b];
    float v[4];
#pragma unroll
    for (int u = 0; u < 4; u++) {
        int t = tid * 4 + u;
        float s = 0.f;
        int ns = 2 * ((t >> 6) + 1);
        for (int j = 0; j < ns; j++) s += r2d[((size_t)b * L + t) * (2 * nT) + j];
        if (bb != 0.f) {  // general Pprev path (skipped in this bench)
            const float* kt = K + ((size_t)b * L + t) * D;
            const float* P = Pprev + (size_t)b * D * D;
            float c = 0.f;
            for (int i = 0; i < D; i++) {
                float w = 0.f;
                for (int j2 = 0; j2 < D; j2++) w += P[i * D + j2] * kt[j2];
                c += kt[i] * w;
            }
            s += 2.f * c;
        }
        v[u] = s;
    }
    v[1] += v[0]; v[2] += v[1]; v[3] += v[2];
    float tot = v[3];
    int lane = tid & 63, wid = tid >> 6;
    float sc = tot;
    for (int off = 1; off < 64; off <<= 1) {
        float n = __shfl_up(sc, off);
        if (lane >= off) sc += n;
    }
    __shared__ float wsum[4];
    if (lane == 63) wsum[wid] = sc;
    __syncthreads();
    float woff = 0.f;
    for (int i = 0; i < wid; i++) woff += wsum[i];
    float exc = woff + sc - tot;
#pragma unroll
    for (int u = 0; u < 4; u++) {
        int t = tid * 4 + u;
        float fro2 = bb + exc + v[u];
        invfro[(size_t)b * L + t] = 1.f / (sqrtf(fro2) + 1e-7f);
    }
}

// ---- Y = tril(S) @ K via MFMA (A = compact S tiles, B = KT rows), fused epilogue. ----
__global__ __launch_bounds__(256) void k_y2(const unsigned short* __restrict__ Sc,
                                            const unsigned short* __restrict__ KT,
                                            const float* __restrict__ invfro,
                                            const float* __restrict__ Q, const float* __restrict__ Pprev,
                                            const float* __restrict__ base,
                                            const float* __restrict__ log_gain, const float* __restrict__ oscale,
                                            float* __restrict__ out, int L, int D, int nT, int nPairs) {
    int nDj = D >> 6;
    int x = blockIdx.x;
    int dj = x % nDj; x /= nDj;
    int ti = x % nT;
    int b = x / nT;
    const unsigned short* ScB = Sc + ((size_t)b * nPairs << 12);
    const unsigned short* KTb = KT + (size_t)b * D * L;
    int w = threadIdx.x >> 6, lane = threadIdx.x & 63;
    int wr = w >> 1, wc = w & 1;
    int twl = wr * 32;             // t-offset within tile
    int dw = dj * 64 + wc * 32;
    int fr = lane & 15, fq = lane >> 4;

    f32x4 a00 = {0,0,0,0}, a01 = {0,0,0,0}, a10 = {0,0,0,0}, a11 = {0,0,0,0};
    int pbase = ti * (ti + 1) / 2;
    for (int sj = 0; sj <= ti; sj++) {
        const unsigned short* Sp = ScB + ((size_t)(pbase + sj) << 12);
        int s0 = sj * 64;
#pragma unroll
        for (int sc = 0; sc < 64; sc += 32) {
            bf16x8 sa0 = ldfrag(Sp + twl * 64 + sc, 64);
            bf16x8 sa1 = ldfrag(Sp + (twl + 16) * 64 + sc, 64);
            bf16x8 kb0 = ldfrag(KTb + (size_t)dw * L + s0 + sc, L);
            bf16x8 kb1 = ldfrag(KTb + (size_t)(dw + 16) * L + s0 + sc, L);
            a00 = __builtin_amdgcn_mfma_f32_16x16x32_bf16(sa0, kb0, a00, 0, 0, 0);
            a01 = __builtin_amdgcn_mfma_f32_16x16x32_bf16(sa0, kb1, a01, 0, 0, 0);
            a10 = __builtin_amdgcn_mfma_f32_16x16x32_bf16(sa1, kb0, a10, 0, 0, 0);
            a11 = __builtin_amdgcn_mfma_f32_16x16x32_bf16(sa1, kb1, a11, 0, 0, 0);
        }
    }

    if (base[b] != 0.f) {  // general Pprev path: Y += Q Pprev^T (skipped in this bench)
        const float* Qf = Q + (size_t)b * L * D;
        const float* Pb = Pprev + (size_t)b * D * D;
        for (int jj = 0; jj < D; jj++) {
            float p0 = Pb[(size_t)(dw + fr) * D + jj];
            float p1 = Pb[(size_t)(dw + 16 + fr) * D + jj];
#define PADD(MI, A0, A1) { _Pragma("unroll") for (int reg = 0; reg < 4; reg++) { \
            float qv = Qf[(size_t)(ti * 64 + twl + MI * 16 + fq * 4 + reg) * D + jj]; \
            A0[reg] += qv * p0; A1[reg] += qv * p1; } }
            PADD(0, a00, a01) PADD(1, a10, a11)
#undef PADD
        }
    }

    float g0 = expf(log_gain[dw + fr]);
    float g1 = expf(log_gain[dw + 16 + fr]);
    float os0 = oscale[dw + fr], os1 = oscale[dw + 16 + fr];
    float* outb = out + (size_t)b * L * D;
#define YEPI(MI, NI, ACC, GG, OS) { _Pragma("unroll") \
    for (int reg = 0; reg < 4; reg++) { \
        int t = ti * 64 + twl + MI * 16 + fq * 4 + reg; \
        int d = dw + NI * 16 + fr; \
        float inv = invfro[(size_t)b * L + t]; \
        outb[(size_t)t * D + d] = tanhf(GG * ACC[reg] * inv) * OS; \
    } }
    YEPI(0, 0, a00, g0, os0) YEPI(0, 1, a01, g1, os1)
    YEPI(1, 0, a10, g0, os0) YEPI(1, 1, a11, g1, os1)
#undef YEPI
}

// K^T K partials over 4 L-chunks, fp32 (precision). One WG per (b, ij-tile, lc).
__global__ __launch_bounds__(256) void k_p(const float* __restrict__ K, float* __restrict__ P4,
                                           int L, int D) {
    int nDj = D >> 6;
    int nIJ = nDj * nDj;
    int x = blockIdx.x;
    int lc = x & 3; x >>= 2;
    int ij = x % nIJ;
    int b = x / nIJ;
    int ib = (ij / nDj) * 64, jb = (ij % nDj) * 64;
    int tchunk = L >> 2;
    int tstart = lc * tchunk;
    const float* Kb = K + (size_t)b * L * D;

    __shared__ float lA[32 * LDSPAD];
    __shared__ float lB[32 * LDSPAD];
    int tid = threadIdx.x, tx = tid & 15, ty = tid >> 4;
    float acc[4][4] = {};

    for (int tc = 0; tc < tchunk; tc += 32) {
        __syncthreads();
        for (int f = tid; f < 512; f += 256) {
            int r = f >> 4, c4 = (f & 15) * 4;
            float4 av = *(const float4*)(Kb + (size_t)(tstart + tc + r) * D + ib + c4);
            *(float4*)&lA[r * LDSPAD + c4] = av;
            float4 bv = *(const float4*)(Kb + (size_t)(tstart + tc + r) * D + jb + c4);
            *(float4*)&lB[r * LDSPAD + c4] = bv;
        }
        __syncthreads();
#pragma unroll 8
        for (int t = 0; t < 32; t++) {
            float4 av = *(const float4*)&lA[t * LDSPAD + ty * 4];
            float4 bv = *(const float4*)&lB[t * LDSPAD + tx * 4];
            float aa[4] = {av.x, av.y, av.z, av.w};
            float ba[4] = {bv.x, bv.y, bv.z, bv.w};
#pragma unroll
            for (int i = 0; i < 4; i++)
#pragma unroll
                for (int j = 0; j < 4; j++) acc[i][j] += aa[i] * ba[j];
        }
    }
    float* dst = P4 + ((((size_t)b * nIJ + ij) * 4 + lc) * 4096);
#pragma unroll
    for (int i = 0; i < 4; i++) {
        float4 o = {acc[i][0], acc[i][1], acc[i][2], acc[i][3]};
        *(float4*)(dst + (ty * 4 + i) * 64 + tx * 4) = o;
    }
}

__global__ void k_pred(const float* __restrict__ Pprev, const float* __restrict__ P4,
                       float* __restrict__ outP, int B, int D) {
    int nDj = D >> 6;
    int nIJ = nDj * nDj;
    size_t e4 = (size_t)blockIdx.x * blockDim.x + threadIdx.x;
    size_t n4 = (size_t)B * D * D / 4;
    if (e4 >= n4) return;
    size_t e = e4 * 4;
    int b = (int)(e / ((size_t)D * D));
    int rem = (int)(e % ((size_t)D * D));
    int i = rem / D, j = rem % D;
    int ij = (i >> 6) * nDj + (j >> 6);
    int li = i & 63, lj = j & 63;
    const float* src = P4 + ((size_t)b * nIJ + ij) * 4 * 4096 + li * 64 + lj;
    float4 pp = *(const float4*)(Pprev + e);
    float4 a0 = *(const float4*)(src + 0 * 4096);
    float4 a1 = *(const float4*)(src + 1 * 4096);
    float4 a2 = *(const float4*)(src + 2 * 4096);
    float4 a3 = *(const float4*)(src + 3 * 4096);
    float4 o;
    o.x = pp.x + a0.x + a1.x + a2.x + a3.x;
    o.y = pp.y + a0.y + a1.y + a2.y + a3.y;
    o.z = pp.z + a0.z + a1.z + a2.z + a3.z;
    o.w = pp.w + a0.w + a1.w + a2.w + a3.w;
    *(float4*)(outP + e) = o;
}

extern "C" void kernel_launch(void* const* d_in, const int* in_sizes, int n_in,
                              void* d_out, int out_size, void* d_ws, size_t ws_size,
                              hipStream_t stream) {
    const float* q = (const float*)d_in[0];
    const float* k = (const float*)d_in[1];
    const float* Pprev = (const float*)d_in[2];
    const float* log_gain = (const float*)d_in[3];
    const float* oscale = (const float*)d_in[4];

    int D = in_sizes[3];                 // 256
    int B = in_sizes[2] / (D * D);       // 4
    int L = in_sizes[0] / (B * D);       // 1024
    int nT = L / 64;                     // 16
    int nPairs = nT * (nT + 1) / 2;      // 136
    int nDt = D >> 6;                    // 4
    int nLt = L >> 6;                    // 16
    int nIJ = nDt * nDt;                 // 16

    float* out = (float*)d_out;
    float* outP = out + (size_t)B * L * D;

    size_t sR = (size_t)B * L * 2 * nT;            // r2d fp32
    size_t sI = (size_t)B * L;                     // invfro
    size_t sBase = 16;
    size_t sP4 = (size_t)B * nIJ * 4 * 4096;       // fp32
    size_t sSc = (size_t)B * nPairs * 4096;        // bf16 elems
    size_t sQK = (size_t)B * L * D;                // bf16 elems each
    size_t need = (sR + sI + sBase + sP4) * sizeof(float) + (sSc + 3 * sQK) * 2;
    if (ws_size < need) return;  // insufficient scratch -> fail validation loudly

    float* r2d = (float*)d_ws;
    float* invfro = r2d + sR;
    float* base = invfro + sI;
    float* P4 = base + sBase;
    unsigned short* Sc = (unsigned short*)(P4 + sP4);
    unsigned short* Qb16 = Sc + sSc;
    unsigned short* Kb16 = Qb16 + sQK;
    unsigned short* KT16 = Kb16 + sQK;

    k_cvt<<<B * nLt * nDt, 256, 0, stream>>>(q, k, Qb16, Kb16, KT16, L, D);
    k_base<<<B, 256, 0, stream>>>(Pprev, base, D);
    k_gs<<<B * nPairs, 256, 0, stream>>>(Qb16, Kb16, Sc, r2d, L, D, nT, nPairs);
    k_scan<<<B, 256, 0, stream>>>(k, Pprev, r2d, base, invfro, L, D, nT);
    k_y2<<<B * nT * nDt, 256, 0, stream>>>(Sc, KT16, invfro, q, Pprev, base, log_gain, oscale,
                                           out, L, D, nT, nPairs);
    k_p<<<B * nIJ * 4, 256, 0, stream>>>(k, P4, L, D);
    k_pred<<<(int)(((size_t)B * D * D / 4 + 255) / 256), 256, 0, stream>>>(Pprev, P4, outP, B, D);
}